// Round 3
// baseline (183.105 us; speedup 1.0000x reference)
//
#include <hip/hip_runtime.h>
#include <math.h>

#define SEQ 512
#define FDIM 64
#define D 8
#define NCH 4              // t-chunks (wave w -> chunk = w & 3)
#define CHLEN (SEQ / NCH)  // 128

__global__ __launch_bounds__(512, 1) void hybrid_attn_kernel(
    const float* __restrict__ state,    // [B,S,F]
    const float* __restrict__ proj_w,   // [F,D]
    const float* __restrict__ proj_b,   // [D]
    const float* __restrict__ rotation, // [D,D]
    const float* __restrict__ entangle, // [D,D]
    const float* __restrict__ w1,       // [D,32]
    const float* __restrict__ b1,       // [32]
    const float* __restrict__ w2,       // [32,16]
    const float* __restrict__ b2,       // [16]
    const float* __restrict__ w3,       // [16,1]
    const float* __restrict__ b3,       // [1]
    float* __restrict__ out)            // [B,S]
{
    __shared__ __align__(16) float s_proj[SEQ][D];   // 16 KB (also V)
    __shared__ __align__(16) float s_k[SEQ][D];      // 16 KB
    __shared__ float s_part[SEQ][9];                 // 18 KB: l + acc[8] per query
    __shared__ float s_cmax[SEQ][NCH];               // 8 KB: per-(query,chunk) max
    __shared__ float s_m[SEQ];                       // 2 KB: per-query max
    __shared__ float s_pw[FDIM][D];                  // 2 KB
    __shared__ float s_rot[D][D];
    __shared__ float s_pb[D];
    __shared__ float s_w1[D * 32];
    __shared__ float s_b1[32];
    __shared__ float s_w2[32 * 16];
    __shared__ float s_b2[16];
    __shared__ float s_w3[16];
    __shared__ float s_b3[1];

    const int b   = blockIdx.x;
    const int tid = threadIdx.x;

    // ---- stage small weights into LDS ----
    if (tid < FDIM * D) s_pw[tid >> 3][tid & 7] = proj_w[tid];
    if (tid < D * D)    s_rot[tid >> 3][tid & 7] = rotation[tid];
    if (tid < D)        s_pb[tid] = proj_b[tid];
    if (tid < D * 32)   s_w1[tid] = w1[tid];
    if (tid < 32)       s_b1[tid] = b1[tid];
    if (tid < 32 * 16)  s_w2[tid] = w2[tid];
    if (tid < 16)       s_b2[tid] = b2[tid];
    if (tid < 16)       s_w3[tid] = w3[tid];
    if (tid == 0)       s_b3[0]   = b3[0];
    __syncthreads();   // staging must be visible before phase 1 (R2 bug!)

    // ---- phase 1: proj = state @ proj_w + b ; k = proj @ entangle ----
    float pj[D];
    #pragma unroll
    for (int j = 0; j < D; j++) pj[j] = s_pb[j];

    const float4* srp = (const float4*)(state + ((size_t)b * SEQ + tid) * FDIM);
    #pragma unroll
    for (int c = 0; c < FDIM / 4; c++) {
        float4 v = srp[c];
        float vs[4] = {v.x, v.y, v.z, v.w};
        #pragma unroll
        for (int u = 0; u < 4; u++) {
            #pragma unroll
            for (int j = 0; j < D; j++) pj[j] += vs[u] * s_pw[c * 4 + u][j];
        }
    }
    {
        float kk[D];
        #pragma unroll
        for (int j = 0; j < D; j++) {
            float ak = 0.f;
            #pragma unroll
            for (int i = 0; i < D; i++) ak += pj[i] * entangle[i * D + j];
            kk[j] = ak;
        }
        #pragma unroll
        for (int j = 0; j < D; j++) { s_proj[tid][j] = pj[j]; s_k[tid][j] = kk[j]; }
    }
    #pragma unroll
    for (int f = 0; f < 9; f++) s_part[tid][f] = 0.f;
    __syncthreads();

    // ---- per-thread query setup: 4 queries, 1 t-chunk ----
    const float scale = 0.35355339059327373f;  // 1/sqrt(8)
    const int w  = tid >> 6;
    const int L  = tid & 63;
    const int g  = w >> 2;        // query group: 0 -> [0,256), 1 -> [256,512)
    const int c  = w & 3;         // t-chunk
    const int q0 = g * 256 + L;   // queries q0 + j*64, j=0..3
    const int tbase = c * CHLEN;

    float qf[4][D];               // scale folded in
    #pragma unroll
    for (int j = 0; j < 4; j++) {
        const int qr = q0 + j * 64;
        float pr[D];
        #pragma unroll
        for (int i = 0; i < D; i++) pr[i] = s_proj[qr][i];
        #pragma unroll
        for (int d2 = 0; d2 < D; d2++) {
            float a = 0.f;
            #pragma unroll
            for (int i = 0; i < D; i++) a += pr[i] * s_rot[i][d2];
            qf[j][d2] = a * scale;
        }
    }

    // ---- pass A: per-(query,chunk) score max ----
    float mx[4] = {-1e30f, -1e30f, -1e30f, -1e30f};
    #pragma unroll 2
    for (int i = 0; i < CHLEN; i++) {
        const float4* kt = (const float4*)s_k[tbase + i];  // wave-uniform broadcast
        float4 k0 = kt[0], k1 = kt[1];
        #pragma unroll
        for (int j = 0; j < 4; j++) {
            float sc = qf[j][0]*k0.x + qf[j][1]*k0.y + qf[j][2]*k0.z + qf[j][3]*k0.w
                     + qf[j][4]*k1.x + qf[j][5]*k1.y + qf[j][6]*k1.z + qf[j][7]*k1.w;
            mx[j] = fmaxf(mx[j], sc);
        }
    }
    #pragma unroll
    for (int j = 0; j < 4; j++) s_cmax[q0 + j * 64][c] = mx[j];
    __syncthreads();

    // reduce chunk maxes -> per-query max
    s_m[tid] = fmaxf(fmaxf(s_cmax[tid][0], s_cmax[tid][1]),
                     fmaxf(s_cmax[tid][2], s_cmax[tid][3]));
    __syncthreads();

    // ---- pass B: exp-sum + weighted V accumulation ----
    float mq[4];
    #pragma unroll
    for (int j = 0; j < 4; j++) mq[j] = s_m[q0 + j * 64];

    float l[4] = {0.f, 0.f, 0.f, 0.f};
    float acc[4][D];
    #pragma unroll
    for (int j = 0; j < 4; j++)
        #pragma unroll
        for (int d2 = 0; d2 < D; d2++) acc[j][d2] = 0.f;

    #pragma unroll 2
    for (int i = 0; i < CHLEN; i++) {
        const int t = tbase + i;
        const float4* kt = (const float4*)s_k[t];
        const float4* pt = (const float4*)s_proj[t];
        float4 k0 = kt[0], k1 = kt[1];
        float4 p0 = pt[0], p1 = pt[1];
        #pragma unroll
        for (int j = 0; j < 4; j++) {
            float sc = qf[j][0]*k0.x + qf[j][1]*k0.y + qf[j][2]*k0.z + qf[j][3]*k0.w
                     + qf[j][4]*k1.x + qf[j][5]*k1.y + qf[j][6]*k1.z + qf[j][7]*k1.w;
            float p = __expf(sc - mq[j]);
            l[j] += p;
            acc[j][0] += p * p0.x; acc[j][1] += p * p0.y;
            acc[j][2] += p * p0.z; acc[j][3] += p * p0.w;
            acc[j][4] += p * p1.x; acc[j][5] += p * p1.y;
            acc[j][6] += p * p1.z; acc[j][7] += p * p1.w;
        }
    }

    // merge partials across the 4 chunk-waves (LDS float atomics)
    #pragma unroll
    for (int j = 0; j < 4; j++) {
        const int qr = q0 + j * 64;
        atomicAdd(&s_part[qr][0], l[j]);
        #pragma unroll
        for (int d2 = 0; d2 < D; d2++) atomicAdd(&s_part[qr][1 + d2], acc[j][d2]);
    }
    __syncthreads();

    // ---- phase 3: normalize + MLP head, one thread per query ----
    const float inv_l = 1.0f / s_part[tid][0];
    float attn[D];
    #pragma unroll
    for (int j = 0; j < D; j++) attn[j] = s_part[tid][1 + j] * inv_l;

    float h1[32];
    #pragma unroll
    for (int j = 0; j < 32; j++) {
        float a = s_b1[j];
        #pragma unroll
        for (int i = 0; i < D; i++) a += attn[i] * s_w1[i * 32 + j];
        h1[j] = fmaxf(a, 0.f);
    }
    float h2[16];
    #pragma unroll
    for (int j = 0; j < 16; j++) {
        float a = s_b2[j];
        #pragma unroll
        for (int i = 0; i < 32; i++) a += h1[i] * s_w2[i * 16 + j];
        h2[j] = fmaxf(a, 0.f);
    }
    float o = s_b3[0];
    #pragma unroll
    for (int i = 0; i < 16; i++) o += h2[i] * s_w3[i];

    out[(size_t)b * SEQ + tid] = o;
}

extern "C" void kernel_launch(void* const* d_in, const int* in_sizes, int n_in,
                              void* d_out, int out_size, void* d_ws, size_t ws_size,
                              hipStream_t stream) {
    const float* state    = (const float*)d_in[0];
    const float* proj_w   = (const float*)d_in[1];
    const float* proj_b   = (const float*)d_in[2];
    const float* rotation = (const float*)d_in[3];
    const float* entangle = (const float*)d_in[4];
    const float* w1       = (const float*)d_in[5];
    const float* b1       = (const float*)d_in[6];
    const float* w2       = (const float*)d_in[7];
    const float* b2       = (const float*)d_in[8];
    const float* w3       = (const float*)d_in[9];
    const float* b3       = (const float*)d_in[10];
    float* out = (float*)d_out;

    const int B = in_sizes[0] / (SEQ * FDIM);  // 256
    hybrid_attn_kernel<<<B, SEQ, 0, stream>>>(
        state, proj_w, proj_b, rotation, entangle,
        w1, b1, w2, b2, w3, b3, out);
}